// Round 14
// baseline (294.173 us; speedup 1.0000x reference)
//
#include <hip/hip_runtime.h>
#include <hip/hip_bf16.h>

// R14: overlap + MLP round.
//  K1 fused: blocks [0,P1B) run part1 (bucket partition, 4KB LDS use),
//     blocks [P1B,..) run node_gemm (32-row tile, 48KB LDS). Independent
//     inputs -> VALU-bound gemm hides under memory-bound partition.
//     NOTE: temp and h no longer alias (they'd race when fused).
//  K2 scanB, K3 part2: unchanged from R13.
//  K4 gather: TWO nodes per wave, interleaved 16-edge groups -> 64 loads in
//     flight for the common deg<=16 case (was 32). VGPR ~100, ~20 waves/CU.

#define SCAN_E 1024
#define EPB 2048            // edges per part1 block
#define NBMAX 512           // max buckets (N <= 131072)
#define CAPB 5120           // temp entries per bucket (mean 4096 + 16 sigma)
#define GEMM_ROWS 32

__global__ __launch_bounds__(256) void init_k(int* __restrict__ bcur, int NB) {
  const int i = blockIdx.x * blockDim.x + threadIdx.x;
  if (i < NB) bcur[i] = i * CAPB;
}

// Fused: part1 (bucket partition) + node_gemm. Entry packing:
// rowlocal<<38 | eid<<17 | col  (needs N < 2^17, E < 2^21).
__global__ __launch_bounds__(256) void fused1_k(
    const int* __restrict__ ei, unsigned long long* __restrict__ temp,
    int* __restrict__ bcur, int E, int NB, int P1B,
    const float* __restrict__ x, const float* __restrict__ W,
    const float* __restrict__ b, float* __restrict__ h, int N) {
  __shared__ __align__(16) char smem[49152];   // 48 KB union
  const int t = threadIdx.x;
  if (blockIdx.x < P1B) {
    // ---------------- part1 role ----------------
    int* hist = (int*)smem;
    int* base = hist + NBMAX;
    for (int i = t; i < NB; i += 256) hist[i] = 0;
    __syncthreads();
    const int e0 = blockIdx.x * EPB;
#pragma unroll
    for (int i = 0; i < EPB / 256; ++i) {
      const int e = e0 + i * 256 + t;
      if (e < E) atomicAdd(&hist[ei[e] >> 8], 1);
    }
    __syncthreads();
    for (int i = t; i < NB; i += 256) {
      const int c = hist[i];
      base[i] = c ? atomicAdd(&bcur[i], c) : 0;
      hist[i] = 0;  // reuse as run cursor
    }
    __syncthreads();
#pragma unroll
    for (int i = 0; i < EPB / 256; ++i) {
      const int e = e0 + i * 256 + t;
      if (e >= E) continue;
      const int row = ei[e];
      const unsigned long long col =
          (unsigned long long)(unsigned int)ei[(size_t)E + e];
      const int bk = row >> 8;
      const int pos = base[bk] + atomicAdd(&hist[bk], 1);
      if (pos < (bk + 1) * CAPB)  // clamp: overflow drops (16-sigma margin)
        temp[pos] = ((unsigned long long)(row & 255) << 38) |
                    ((unsigned long long)(unsigned int)e << 17) | col;
    }
  } else {
    // ---------------- node_gemm role (32-row tile) ----------------
    float* xl = (float*)smem;            // 32*128 f32 = 16 KB
    float* wl = xl + GEMM_ROWS * 128;    // 128*64 f32 = 32 KB
    const int bid = blockIdx.x - P1B;
    for (int i = t; i < 128 * 64 / 4; i += 256)
      ((float4*)wl)[i] = ((const float4*)W)[i];
    const int r0 = bid * GEMM_ROWS;
    for (int i = t; i < GEMM_ROWS * 32; i += 256) {   // 1024 float4, coalesced
      const int rr = i >> 5;
      const int kk = i & 31;
      const int gr = (r0 + rr < N) ? (r0 + rr) : (N - 1);
      ((float4*)xl)[i] = ((const float4*)(x + (size_t)gr * 128))[kk];
    }
    __syncthreads();
    const int c = t & 63;
    const int wv = t >> 6;               // wave: rows wv*8 .. +7
    const float bias = b[c];
    float acc[8];
#pragma unroll
    for (int i = 0; i < 8; ++i) acc[i] = bias;
#pragma unroll 2
    for (int k = 0; k < 128; k += 4) {
      const float w0 = wl[(k + 0) * 64 + c];   // stride-1 lanes: conflict-free
      const float w1 = wl[(k + 1) * 64 + c];
      const float w2 = wl[(k + 2) * 64 + c];
      const float w3 = wl[(k + 3) * 64 + c];
#pragma unroll
      for (int i = 0; i < 8; ++i) {
        const float4 x4 = *(const float4*)&xl[(wv * 8 + i) * 128 + k];
        acc[i] = fmaf(x4.x, w0, acc[i]);
        acc[i] = fmaf(x4.y, w1, acc[i]);
        acc[i] = fmaf(x4.z, w2, acc[i]);
        acc[i] = fmaf(x4.w, w3, acc[i]);
      }
    }
#pragma unroll
    for (int i = 0; i < 8; ++i) {
      const int r = r0 + wv * 8 + i;
      if (r < N) h[(size_t)r * 64 + c] = acc[i];
    }
  }
}

// One block: exclusive scan of bucket totals -> compacted CSR bucket bases.
__global__ __launch_bounds__(512) void scanB_k(const int* __restrict__ bcur,
                                               int* __restrict__ bbase, int NB) {
  __shared__ int sd[512];
  const int t = threadIdx.x;
  int tot = 0;
  if (t < NB) {
    const int end = min(bcur[t], (t + 1) * CAPB);
    tot = end - t * CAPB;
  }
  sd[t] = tot;
  __syncthreads();
  for (int off = 1; off < 512; off <<= 1) {
    int val = sd[t];
    int add = (t >= off) ? sd[t - off] : 0;
    __syncthreads();
    sd[t] = val + add;
    __syncthreads();
  }
  if (t < NB) bbase[t] = sd[t] - tot;  // exclusive
}

// One block per bucket: LDS row counts + scan -> offs/deg + compacted list.
__global__ __launch_bounds__(256) void part2_k(
    const unsigned long long* __restrict__ temp, const int* __restrict__ bcur,
    const int* __restrict__ bbase, unsigned long long* __restrict__ list,
    int* __restrict__ offs, int* __restrict__ deg, int N, int NB) {
  __shared__ int cnt[256];
  __shared__ int sd[256];
  __shared__ int lcur[256];
  const int b = blockIdx.x;
  const int t = threadIdx.x;
  const int r0 = b << 8;
  cnt[t] = 0;
  __syncthreads();
  const int start = b * CAPB;
  const int end = min(bcur[b], start + CAPB);
  for (int i = start + t; i < end; i += 256)
    atomicAdd(&cnt[(int)(temp[i] >> 38)], 1);
  __syncthreads();
  sd[t] = cnt[t];
  __syncthreads();
  for (int off = 1; off < 256; off <<= 1) {
    int val = sd[t];
    int add = (t >= off) ? sd[t - off] : 0;
    __syncthreads();
    sd[t] = val + add;
    __syncthreads();
  }
  const int gbase = bbase[b] + sd[t] - cnt[t];
  lcur[t] = gbase;
  const int r = r0 + t;
  if (r < N) { offs[r] = gbase; deg[r] = cnt[t]; }
  __syncthreads();
  for (int i = start + t; i < end; i += 256) {
    const unsigned long long ent = temp[i];
    const int rl = (int)(ent >> 38);
    const int pos = atomicAdd(&lcur[rl], 1);  // LDS atomic, block-private
    list[pos] = ent;
  }
}

__global__ __launch_bounds__(256) void gather_k(
    const unsigned long long* __restrict__ list, const int* __restrict__ offs,
    const int* __restrict__ degv, const float* __restrict__ h,
    const float* __restrict__ attr, const float* __restrict__ We,
    const float* __restrict__ be, float* __restrict__ out, int N) {
  __shared__ float wl[32 * 64];  // 8 KB W_edge
  for (int i = threadIdx.x; i < 32 * 64 / 4; i += 256)
    ((float4*)wl)[i] = ((const float4*)We)[i];
  __syncthreads();
  const int lane = threadIdx.x & 63;
  const int nodeA = blockIdx.x * 8 + (threadIdx.x >> 6) * 2;
  const int nodeB = nodeA + 1;
  if (nodeA >= N) return;
  const bool hasB = (nodeB < N);
  // wave-uniform scalars: extraction + addressing on the SALU
  const int baseA = __builtin_amdgcn_readfirstlane(offs[nodeA]);
  const int degA  = __builtin_amdgcn_readfirstlane(degv[nodeA]);
  const int baseB = hasB ? __builtin_amdgcn_readfirstlane(offs[nodeB]) : 0;
  const int degB  = hasB ? __builtin_amdgcn_readfirstlane(degv[nodeB]) : 0;
  float accA = 0.f, accaA = 0.f, accB = 0.f, accaB = 0.f;
  const int jmax = max(degA, degB);
  for (int j = 0; j < jmax; j += 16) {
    float vA[16], aA[16], vB[16], aB[16];
    // Issue ALL of A's and B's loads (independent chains) before any
    // accumulate: up to 64 loads in flight. Guards are wave-uniform.
#pragma unroll
    for (int u = 0; u < 16; ++u) {
      if (j + u < degA) {
        const unsigned long long e2 = list[baseA + j + u];
        const int lo = __builtin_amdgcn_readfirstlane((int)(unsigned int)e2);
        const int hi = __builtin_amdgcn_readfirstlane((int)(unsigned int)(e2 >> 32));
        const int col = lo & 0x1FFFF;
        const int eid = ((unsigned int)lo >> 17) | ((hi & 0x3F) << 15);
        vA[u] = h[(size_t)col * 64 + lane];
        aA[u] = attr[(size_t)eid * 32 + (lane & 31)];
      } else { vA[u] = 0.f; aA[u] = 0.f; }
    }
#pragma unroll
    for (int u = 0; u < 16; ++u) {
      if (j + u < degB) {
        const unsigned long long e2 = list[baseB + j + u];
        const int lo = __builtin_amdgcn_readfirstlane((int)(unsigned int)e2);
        const int hi = __builtin_amdgcn_readfirstlane((int)(unsigned int)(e2 >> 32));
        const int col = lo & 0x1FFFF;
        const int eid = ((unsigned int)lo >> 17) | ((hi & 0x3F) << 15);
        vB[u] = h[(size_t)col * 64 + lane];
        aB[u] = attr[(size_t)eid * 32 + (lane & 31)];
      } else { vB[u] = 0.f; aB[u] = 0.f; }
    }
#pragma unroll
    for (int u = 0; u < 16; ++u) { accA += vA[u]; accaA += aA[u]; }
#pragma unroll
    for (int u = 0; u < 16; ++u) { accB += vB[u]; accaB += aB[u]; }
  }
  // acca (channel k in lane k, dup in k+32) @ W_edge, then normalize + write
  float rA = 0.f, rB = 0.f;
#pragma unroll
  for (int k = 0; k < 32; ++k) {
    const float wk = wl[k * 64 + lane];
    rA += __shfl(accaA, k) * wk;
    rB += __shfl(accaB, k) * wk;
  }
  const float cnA = (float)degA;
  out[(size_t)nodeA * 64 + lane] = (accA + rA + cnA * be[lane]) / fmaxf(cnA, 1.0f);
  if (hasB) {
    const float cnB = (float)degB;
    out[(size_t)nodeB * 64 + lane] = (accB + rB + cnB * be[lane]) / fmaxf(cnB, 1.0f);
  }
}

extern "C" void kernel_launch(void* const* d_in, const int* in_sizes, int n_in,
                              void* d_out, int out_size, void* d_ws, size_t ws_size,
                              hipStream_t stream) {
  const float* x    = (const float*)d_in[0];
  const int*   ei   = (const int*)d_in[1];     // int32 per harness contract
  const float* attr = (const float*)d_in[2];
  const float* Wn   = (const float*)d_in[3];
  const float* bn   = (const float*)d_in[4];
  const float* We   = (const float*)d_in[5];
  const float* be   = (const float*)d_in[6];
  float* out = (float*)d_out;

  const int N = in_sizes[0] / 128;        // 100000
  const int E = in_sizes[2] / 32;         // 1600000
  const int NB = (N + 255) >> 8;          // 391 buckets of 256 rows

  // workspace (temp and h must NOT alias -- they're live concurrently in K1)
  float* h = (float*)d_ws;                                  // N*64 f32 (25.6 MB)
  unsigned long long* list = (unsigned long long*)(h + (size_t)N * 64);  // E*8B
  unsigned long long* temp = list + (size_t)E;              // NB*CAPB*8B (16 MB)
  int* deg   = (int*)(temp + (size_t)NB * CAPB);            // N ints
  int* offs  = deg + N;                                     // N ints
  int* bcur  = offs + N;                                    // NBMAX ints
  int* bbase = bcur + NBMAX;                                // NBMAX ints

  const int P1B = (E + EPB - 1) / EPB;        // 782 part1 blocks
  const int G2  = (N + GEMM_ROWS - 1) / GEMM_ROWS;  // 3125 gemm blocks

  init_k<<<(NB + 255) / 256, 256, 0, stream>>>(bcur, NB);
  fused1_k<<<P1B + G2, 256, 0, stream>>>(ei, temp, bcur, E, NB, P1B,
                                         x, Wn, bn, h, N);
  scanB_k<<<1, 512, 0, stream>>>(bcur, bbase, NB);
  part2_k<<<NB, 256, 0, stream>>>(temp, bcur, bbase, list, offs, deg, N, NB);
  gather_k<<<(N + 7) / 8, 256, 0, stream>>>(list, offs, deg, h, attr, We, be, out, N);
}

// Round 15
// 205.245 us; speedup vs baseline: 1.4333x; 1.4333x over previous
//
#include <hip/hip_runtime.h>
#include <hip/hip_bf16.h>

// R15: keep R14's fused part1+node_gemm (saved ~28us: 83us non-gather vs
// R13's 111us). REVERT gather to R13's single-node 16-group version: R14's
// 2-node variant spilled its 4x16-float arrays to scratch (VGPR_Count=44 <
// 64 floats of arrays => scratch), occupancy 77->48%, 110->211us.
//  K1 init, K2 fused(part1|node_gemm), K3 scanB, K4 part2, K5 gather.

#define EPB 2048            // edges per part1 block
#define NBMAX 512           // max buckets (N <= 131072)
#define CAPB 5120           // temp entries per bucket (mean 4096 + 16 sigma)
#define GEMM_ROWS 32

__global__ __launch_bounds__(256) void init_k(int* __restrict__ bcur, int NB) {
  const int i = blockIdx.x * blockDim.x + threadIdx.x;
  if (i < NB) bcur[i] = i * CAPB;
}

// Fused: part1 (bucket partition) + node_gemm. Entry packing:
// rowlocal<<38 | eid<<17 | col  (needs N < 2^17, E < 2^21).
__global__ __launch_bounds__(256) void fused1_k(
    const int* __restrict__ ei, unsigned long long* __restrict__ temp,
    int* __restrict__ bcur, int E, int NB, int P1B,
    const float* __restrict__ x, const float* __restrict__ W,
    const float* __restrict__ b, float* __restrict__ h, int N) {
  __shared__ __align__(16) char smem[49152];   // 48 KB union
  const int t = threadIdx.x;
  if (blockIdx.x < P1B) {
    // ---------------- part1 role ----------------
    int* hist = (int*)smem;
    int* base = hist + NBMAX;
    for (int i = t; i < NB; i += 256) hist[i] = 0;
    __syncthreads();
    const int e0 = blockIdx.x * EPB;
#pragma unroll
    for (int i = 0; i < EPB / 256; ++i) {
      const int e = e0 + i * 256 + t;
      if (e < E) atomicAdd(&hist[ei[e] >> 8], 1);
    }
    __syncthreads();
    for (int i = t; i < NB; i += 256) {
      const int c = hist[i];
      base[i] = c ? atomicAdd(&bcur[i], c) : 0;
      hist[i] = 0;  // reuse as run cursor
    }
    __syncthreads();
#pragma unroll
    for (int i = 0; i < EPB / 256; ++i) {
      const int e = e0 + i * 256 + t;
      if (e >= E) continue;
      const int row = ei[e];
      const unsigned long long col =
          (unsigned long long)(unsigned int)ei[(size_t)E + e];
      const int bk = row >> 8;
      const int pos = base[bk] + atomicAdd(&hist[bk], 1);
      if (pos < (bk + 1) * CAPB)  // clamp: overflow drops (16-sigma margin)
        temp[pos] = ((unsigned long long)(row & 255) << 38) |
                    ((unsigned long long)(unsigned int)e << 17) | col;
    }
  } else {
    // ---------------- node_gemm role (32-row tile) ----------------
    float* xl = (float*)smem;            // 32*128 f32 = 16 KB
    float* wl = xl + GEMM_ROWS * 128;    // 128*64 f32 = 32 KB
    const int bid = blockIdx.x - P1B;
    for (int i = t; i < 128 * 64 / 4; i += 256)
      ((float4*)wl)[i] = ((const float4*)W)[i];
    const int r0 = bid * GEMM_ROWS;
    for (int i = t; i < GEMM_ROWS * 32; i += 256) {   // 1024 float4, coalesced
      const int rr = i >> 5;
      const int kk = i & 31;
      const int gr = (r0 + rr < N) ? (r0 + rr) : (N - 1);
      ((float4*)xl)[i] = ((const float4*)(x + (size_t)gr * 128))[kk];
    }
    __syncthreads();
    const int c = t & 63;
    const int wv = t >> 6;               // wave: rows wv*8 .. +7
    const float bias = b[c];
    float acc[8];
#pragma unroll
    for (int i = 0; i < 8; ++i) acc[i] = bias;
#pragma unroll 2
    for (int k = 0; k < 128; k += 4) {
      const float w0 = wl[(k + 0) * 64 + c];   // stride-1 lanes: conflict-free
      const float w1 = wl[(k + 1) * 64 + c];
      const float w2 = wl[(k + 2) * 64 + c];
      const float w3 = wl[(k + 3) * 64 + c];
#pragma unroll
      for (int i = 0; i < 8; ++i) {
        const float4 x4 = *(const float4*)&xl[(wv * 8 + i) * 128 + k];
        acc[i] = fmaf(x4.x, w0, acc[i]);
        acc[i] = fmaf(x4.y, w1, acc[i]);
        acc[i] = fmaf(x4.z, w2, acc[i]);
        acc[i] = fmaf(x4.w, w3, acc[i]);
      }
    }
#pragma unroll
    for (int i = 0; i < 8; ++i) {
      const int r = r0 + wv * 8 + i;
      if (r < N) h[(size_t)r * 64 + c] = acc[i];
    }
  }
}

// One block: exclusive scan of bucket totals -> compacted CSR bucket bases.
__global__ __launch_bounds__(512) void scanB_k(const int* __restrict__ bcur,
                                               int* __restrict__ bbase, int NB) {
  __shared__ int sd[512];
  const int t = threadIdx.x;
  int tot = 0;
  if (t < NB) {
    const int end = min(bcur[t], (t + 1) * CAPB);
    tot = end - t * CAPB;
  }
  sd[t] = tot;
  __syncthreads();
  for (int off = 1; off < 512; off <<= 1) {
    int val = sd[t];
    int add = (t >= off) ? sd[t - off] : 0;
    __syncthreads();
    sd[t] = val + add;
    __syncthreads();
  }
  if (t < NB) bbase[t] = sd[t] - tot;  // exclusive
}

// One block per bucket: LDS row counts + scan -> offs/deg + compacted list.
__global__ __launch_bounds__(256) void part2_k(
    const unsigned long long* __restrict__ temp, const int* __restrict__ bcur,
    const int* __restrict__ bbase, unsigned long long* __restrict__ list,
    int* __restrict__ offs, int* __restrict__ deg, int N, int NB) {
  __shared__ int cnt[256];
  __shared__ int sd[256];
  __shared__ int lcur[256];
  const int b = blockIdx.x;
  const int t = threadIdx.x;
  const int r0 = b << 8;
  cnt[t] = 0;
  __syncthreads();
  const int start = b * CAPB;
  const int end = min(bcur[b], start + CAPB);
  for (int i = start + t; i < end; i += 256)
    atomicAdd(&cnt[(int)(temp[i] >> 38)], 1);
  __syncthreads();
  sd[t] = cnt[t];
  __syncthreads();
  for (int off = 1; off < 256; off <<= 1) {
    int val = sd[t];
    int add = (t >= off) ? sd[t - off] : 0;
    __syncthreads();
    sd[t] = val + add;
    __syncthreads();
  }
  const int gbase = bbase[b] + sd[t] - cnt[t];
  lcur[t] = gbase;
  const int r = r0 + t;
  if (r < N) { offs[r] = gbase; deg[r] = cnt[t]; }
  __syncthreads();
  for (int i = start + t; i < end; i += 256) {
    const unsigned long long ent = temp[i];
    const int rl = (int)(ent >> 38);
    const int pos = atomicAdd(&lcur[rl], 1);  // LDS atomic, block-private
    list[pos] = ent;
  }
}

__global__ __launch_bounds__(256) void gather_k(
    const unsigned long long* __restrict__ list, const int* __restrict__ offs,
    const int* __restrict__ degv, const float* __restrict__ h,
    const float* __restrict__ attr, const float* __restrict__ We,
    const float* __restrict__ be, float* __restrict__ out, int N) {
  __shared__ float wl[32 * 64];  // 8 KB W_edge
  for (int i = threadIdx.x; i < 32 * 64 / 4; i += 256)
    ((float4*)wl)[i] = ((const float4*)We)[i];
  __syncthreads();
  const int lane = threadIdx.x & 63;
  const int node = blockIdx.x * 4 + (threadIdx.x >> 6);
  if (node >= N) return;
  // wave-uniform scalars: extraction + addressing run on the SALU
  const int base = __builtin_amdgcn_readfirstlane(offs[node]);
  const int deg  = __builtin_amdgcn_readfirstlane(degv[node]);
  float acc = 0.f, acca = 0.f;
  for (int j = 0; j < deg; j += 16) {
    float v[16], a[16];
    // 16 edges per group, all loads issued before any accumulate. Per-edge
    // guard is wave-uniform (scalar branch): skipped tail costs no VMEM.
#pragma unroll
    for (int u = 0; u < 16; ++u) {
      if (j + u < deg) {
        const unsigned long long e2 = list[base + j + u];   // uniform 8B load
        const int lo = __builtin_amdgcn_readfirstlane((int)(unsigned int)e2);
        const int hi = __builtin_amdgcn_readfirstlane((int)(unsigned int)(e2 >> 32));
        // entry: rl<<38 | eid<<17 | col  (scalar extraction)
        const int col = lo & 0x1FFFF;
        const int eid = ((unsigned int)lo >> 17) | ((hi & 0x3F) << 15);
        v[u] = h[(size_t)col * 64 + lane];               // saddr + lane*4
        a[u] = attr[(size_t)eid * 32 + (lane & 31)];     // dup halves -> 1x128B
      } else {
        v[u] = 0.f; a[u] = 0.f;
      }
    }
#pragma unroll
    for (int u = 0; u < 16; ++u) { acc += v[u]; acca += a[u]; }
  }
  // acca (channel k in lane k, duplicated in lanes k+32) @ W_edge
  float r = 0.f;
#pragma unroll
  for (int k = 0; k < 32; ++k)
    r += __shfl(acca, k) * wl[k * 64 + lane];
  const float cn = (float)deg;
  out[(size_t)node * 64 + lane] = (acc + r + cn * be[lane]) / fmaxf(cn, 1.0f);
}

extern "C" void kernel_launch(void* const* d_in, const int* in_sizes, int n_in,
                              void* d_out, int out_size, void* d_ws, size_t ws_size,
                              hipStream_t stream) {
  const float* x    = (const float*)d_in[0];
  const int*   ei   = (const int*)d_in[1];     // int32 per harness contract
  const float* attr = (const float*)d_in[2];
  const float* Wn   = (const float*)d_in[3];
  const float* bn   = (const float*)d_in[4];
  const float* We   = (const float*)d_in[5];
  const float* be   = (const float*)d_in[6];
  float* out = (float*)d_out;

  const int N = in_sizes[0] / 128;        // 100000
  const int E = in_sizes[2] / 32;         // 1600000
  const int NB = (N + 255) >> 8;          // 391 buckets of 256 rows

  // workspace (temp and h must NOT alias -- they're live concurrently in K2)
  float* h = (float*)d_ws;                                  // N*64 f32 (25.6 MB)
  unsigned long long* list = (unsigned long long*)(h + (size_t)N * 64);  // E*8B
  unsigned long long* temp = list + (size_t)E;              // NB*CAPB*8B (16 MB)
  int* deg   = (int*)(temp + (size_t)NB * CAPB);            // N ints
  int* offs  = deg + N;                                     // N ints
  int* bcur  = offs + N;                                    // NBMAX ints
  int* bbase = bcur + NBMAX;                                // NBMAX ints

  const int P1B = (E + EPB - 1) / EPB;              // 782 part1 blocks
  const int G2  = (N + GEMM_ROWS - 1) / GEMM_ROWS;  // 3125 gemm blocks

  init_k<<<(NB + 255) / 256, 256, 0, stream>>>(bcur, NB);
  fused1_k<<<P1B + G2, 256, 0, stream>>>(ei, temp, bcur, E, NB, P1B,
                                         x, Wn, bn, h, N);
  scanB_k<<<1, 512, 0, stream>>>(bcur, bbase, NB);
  part2_k<<<NB, 256, 0, stream>>>(temp, bcur, bbase, list, offs, deg, N, NB);
  gather_k<<<(N + 3) / 4, 256, 0, stream>>>(list, offs, deg, h, attr, We, be, out, N);
}